// Round 1
// baseline (540.138 us; speedup 1.0000x reference)
//
#include <hip/hip_runtime.h>

// CRITICAL: bit-exact replication of the numpy fp32 oracle requires NO FMA
// contraction (hipcc default -ffp-contract=fast-honor-pragmas would fuse).
#pragma clang fp contract(off)

#define D4    83521      // 17^4 entries per LUT (per channel)
#define HW    262144     // 512*512
#define NPIX  2097152    // 8*512*512
#define QREC  73984      // 17*17*16*16 quad records per LUT (64 B each)
#define CBLK  64         // cooperative kernel: single-wave blocks

// ---------- quad packing: one 64 B record = 2x2 (i2,i3) corner block --------
// Record r = ((i0*17 + i1)*16 + i2)*16 + i3 (i2,i3 in [0,16)); slot g holds
// channels of corner (i2+(g&1), i3+(g>>1)). Verified bit-exact (r7/r11/r12).
__global__ __launch_bounds__(256) void pack_quad(const float* __restrict__ src,
                                                 int n_ch,
                                                 float4* __restrict__ dst) {
    int e = blockIdx.x * 256 + threadIdx.x;
    if (e >= QREC) return;
    int i3 = e & 15;
    int i2 = (e >> 4) & 15;
    int t  = e >> 8;              // i0*17 + i1
    int i0 = t / 17;
    int i1 = t - i0 * 17;
    int base = i0 * 4913 + i1 * 289 + i2 * 17 + i3;
    float4* rec = dst + (size_t)e * 4;
#pragma unroll
    for (int g = 0; g < 4; ++g) {
        int o = base + (g & 1) * 17 + (g >> 1);
        float4 v;
        v.x = src[o];
        v.y = src[D4 + o];
        v.z = src[2 * D4 + o];
        v.w = (n_ch == 4) ? src[3 * D4 + o] : 0.f;
        rec[g] = v;
    }
}

// Cooperative fused 6-stage chain — BARRIER-FREE, TWO-PHASE EXCHANGE (r14).
// r13 was latency-bound at 24% occupancy: LDS 17408 B/block -> 9 blocks/CU.
// The 16-fragment exchange splits cleanly on corner bit b3 (== hi of the
// accumulate loop): a loader lane's fragment has fixed b3 = (tid>>1)&1, so
// phase h writes only those 32 lanes into a COMPRESSED 8-column row
// (col = rec*2 + b2), then all 64 lanes read 8 fragments and accumulate the
// hi==h half. Accumulation order and weight association are bit-identical
// to r13 (phase order == hi order, c=0..7 order preserved). In-wave DS
// program order + sched_barrier(0) keeps read-before-overwrite safe with no
// __syncthreads. LDS: 64 rows x 9 float4 = 9216 B -> 16-17 blocks/CU
// (VGPR=68 caps at 16 waves/CU), ~2x the resident waves of r13.
__global__ __launch_bounds__(CBLK) void fused_coop(const float* __restrict__ vi,
                                                   const float* __restrict__ ir,
                                                   const float4* __restrict__ luts,
                                                   float* __restrict__ out) {
#pragma clang fp contract(off)
    __shared__ float4 exch[CBLK * 9];   // 9216 B, stride-9 rows (conflict-free)

    int tid = threadIdx.x;              // == lane (single-wave block)
    int p = blockIdx.x * CBLK + tid;
    int b  = p >> 18;                   // HW = 2^18
    int hw = p & (HW - 1);
    int vbase = (b * 3) << 18;

    float x0 = vi[vbase + hw];
    float x1 = vi[vbase + HW + hw];
    float x2 = vi[vbase + 2 * HW + hw];
    float x3 = ir[p];

    int rec     = (tid >> 2) & 3;       // loader role: corner (b0,b1)
    int slot    = tid & 3;              // loader role: corner (b2,b3)
    int rec_off = ((rec & 1) ? 4352 : 0) + ((rec & 2) ? 256 : 0);
    int sub     = tid >> 4;             // which pixel of each 4-px group
    int wr_b3   = (tid >> 1) & 1;       // b3 of the fragment this lane loads
    int wr_col  = rec * 2 + (tid & 1);  // compressed col = rec*2 + b2

    for (int s = 0; s < 6; ++s) {
        // per-lane LUT base folds in the role offset (addr calc once)
        const float4* __restrict__ lutS =
            luts + (size_t)s * QREC * 4 + (size_t)rec_off * 4 + slot;

        // ---- owner: indices + weights (exact round-6 arithmetic) ----
        x0 = fminf(fmaxf(x0, 0.f), 1.f);
        x1 = fminf(fmaxf(x1, 0.f), 1.f);
        x2 = fminf(fmaxf(x2, 0.f), 1.f);
        x3 = fminf(fmaxf(x3, 0.f), 1.f);
        float xs0 = x0 * 16.f;
        float xs1 = x1 * 16.f;
        float xs2 = x2 * 16.f;
        float xs3 = x3 * 16.f;
        int i0 = (int)xs0; i0 = i0 > 15 ? 15 : i0;
        int i1 = (int)xs1; i1 = i1 > 15 ? 15 : i1;
        int i2 = (int)xs2; i2 = i2 > 15 ? 15 : i2;
        int i3 = (int)xs3; i3 = i3 > 15 ? 15 : i3;
        float f0 = xs0 - (float)i0;     // mul-then-sub, contraction OFF
        float f1 = xs1 - (float)i1;
        float f2 = xs2 - (float)i2;
        float f3 = xs3 - (float)i3;
        float g0 = 1.f - f0;
        float g1 = 1.f - f1;
        float g2 = 1.f - f2;
        float g3 = 1.f - f3;
        float w01[4] = { g0 * g1, f0 * g1, g0 * f1, f0 * f1 };

        int r00 = ((i0 * 17 + i1) * 16 + i2) * 16 + i3;

        // ---- r00 exchange: pure in-wave shuffle, no LDS / no barrier ----
        int r0s[16];
#pragma unroll
        for (int t = 0; t < 16; ++t)
            r0s[t] = __shfl(r00, 4 * t + sub, 64);

        // ---- cooperative gather: 16 loads/lane, coalesced 64 B records ----
        float4 v[16];
#pragma unroll
        for (int t = 0; t < 16; ++t)
            v[t] = lutS[(size_t)r0s[t] * 4];
        __builtin_amdgcn_sched_barrier(0);   // keep the 16-deep load batch intact

        float a0 = 0.f, a1 = 0.f, a2 = 0.f, a3 = 0.f;
        const float4* myb = &exch[tid * 9];

        // ---- phase h = hi (b3): write compressed half, read, accumulate ----
#pragma unroll
        for (int h = 0; h < 2; ++h) {
            if (wr_b3 == h) {               // 32 writer lanes, all 64 rows
#pragma unroll
                for (int t = 0; t < 16; ++t)
                    exch[(4 * t + sub) * 9 + wr_col] = v[t];
            }
            __builtin_amdgcn_sched_barrier(0);   // pin write->read program order

            float w3 = h ? f3 : g3;
#pragma unroll
            for (int c = 0; c < 8; ++c) {   // b0=c&1, b1=(c>>1)&1, b2=c>>2
                float4 vv = myb[(c & 3) * 2 + (c >> 2)];
                float w012 = w01[c & 3] * ((c >> 2) ? f2 : g2);
                float w    = w012 * w3;
                if (h == 0 && c == 0) {
                    a0 = vv.x * w; a1 = vv.y * w; a2 = vv.z * w; a3 = vv.w * w;
                } else {
                    a0 = a0 + vv.x * w; a1 = a1 + vv.y * w;
                    a2 = a2 + vv.z * w; a3 = a3 + vv.w * w;
                }
            }
            __builtin_amdgcn_sched_barrier(0);   // reads done before next writes
        }
        x0 = a0; x1 = a1; x2 = a2; x3 = a3;
    }

    out[vbase + hw]          = x0;
    out[vbase + HW + hw]     = x1;
    out[vbase + 2 * HW + hw] = x2;
}

// ---------- middle tier: round-10 fused kernel (proven, 653 us) -------------
__global__ __launch_bounds__(256) void pack_kernel(const float* __restrict__ src,
                                                   int n_ch,
                                                   float4* __restrict__ dst) {
    int e = blockIdx.x * 256 + threadIdx.x;
    if (e >= D4) return;
    float4 v;
    v.x = src[e];
    v.y = src[D4 + e];
    v.z = src[2 * D4 + e];
    v.w = (n_ch == 4) ? src[3 * D4 + e] : 0.f;
    dst[e] = v;
}

__global__ __launch_bounds__(256) void fused_mlp(const float* __restrict__ vi,
                                                 const float* __restrict__ ir,
                                                 const float4* __restrict__ luts,
                                                 float* __restrict__ out) {
#pragma clang fp contract(off)
    int p = blockIdx.x * 256 + threadIdx.x;
    if (p >= NPIX) return;
    int b  = p >> 18;
    int hw = p & (HW - 1);
    int vbase = (b * 3) << 18;

    float x0 = vi[vbase + hw];
    float x1 = vi[vbase + HW + hw];
    float x2 = vi[vbase + 2 * HW + hw];
    float x3 = ir[p];

    for (int s = 0; s < 6; ++s) {
        const float4* __restrict__ lut = luts + (size_t)s * D4;
        x0 = fminf(fmaxf(x0, 0.f), 1.f);
        x1 = fminf(fmaxf(x1, 0.f), 1.f);
        x2 = fminf(fmaxf(x2, 0.f), 1.f);
        x3 = fminf(fmaxf(x3, 0.f), 1.f);
        float xs0 = x0 * 16.f;
        float xs1 = x1 * 16.f;
        float xs2 = x2 * 16.f;
        float xs3 = x3 * 16.f;
        int i0 = (int)xs0; i0 = i0 > 15 ? 15 : i0;
        int i1 = (int)xs1; i1 = i1 > 15 ? 15 : i1;
        int i2 = (int)xs2; i2 = i2 > 15 ? 15 : i2;
        int i3 = (int)xs3; i3 = i3 > 15 ? 15 : i3;
        float f0 = xs0 - (float)i0;
        float f1 = xs1 - (float)i1;
        float f2 = xs2 - (float)i2;
        float f3 = xs3 - (float)i3;
        float g0 = 1.f - f0;
        float g1 = 1.f - f1;
        float g2 = 1.f - f2;
        float g3 = 1.f - f3;
        float w01[4] = { g0 * g1, f0 * g1, g0 * f1, f0 * f1 };
        int off = i0 * 4913 + i1 * 289 + i2 * 17 + i3;

        float4 v[16];
#pragma unroll
        for (int hi = 0; hi < 2; ++hi) {
#pragma unroll
            for (int c = 0; c < 8; ++c) {
                int d = (c & 1) * 4913 + ((c >> 1) & 1) * 289 + (c >> 2) * 17 + hi;
                v[hi * 8 + c] = lut[off + d];
            }
        }
        __builtin_amdgcn_sched_barrier(0);

        float a0 = 0.f, a1 = 0.f, a2 = 0.f, a3 = 0.f;
#pragma unroll
        for (int hi = 0; hi < 2; ++hi) {
            float w3 = hi ? f3 : g3;
#pragma unroll
            for (int c = 0; c < 8; ++c) {
                float4 vv = v[hi * 8 + c];
                float w012 = w01[c & 3] * ((c >> 2) ? f2 : g2);
                float w    = w012 * w3;
                if (hi == 0 && c == 0) {
                    a0 = vv.x * w; a1 = vv.y * w; a2 = vv.z * w; a3 = vv.w * w;
                } else {
                    a0 = a0 + vv.x * w; a1 = a1 + vv.y * w;
                    a2 = a2 + vv.z * w; a3 = a3 + vv.w * w;
                }
            }
        }
        x0 = a0; x1 = a1; x2 = a2; x3 = a3;
    }

    out[vbase + hw]          = x0;
    out[vbase + HW + hw]     = x1;
    out[vbase + 2 * HW + hw] = x2;
}

// ---------- raw fallback (no workspace) -------------------------------------
__global__ __launch_bounds__(256) void fused_fallback(const float* __restrict__ vi,
                                                      const float* __restrict__ ir,
                                                      const float* __restrict__ l8,
                                                      const float* __restrict__ l00,
                                                      const float* __restrict__ l01,
                                                      const float* __restrict__ l02,
                                                      const float* __restrict__ l03,
                                                      const float* __restrict__ lpgf,
                                                      float* __restrict__ out) {
#pragma clang fp contract(off)
    int p = blockIdx.x * 256 + threadIdx.x;
    if (p >= NPIX) return;
    int b  = p >> 18;
    int hw = p & (HW - 1);
    int vbase = (b * 3) << 18;

    const float* ptrs[6] = { l8, l00, l01, l02, l03, lpgf };

    float x0 = vi[vbase + hw];
    float x1 = vi[vbase + HW + hw];
    float x2 = vi[vbase + 2 * HW + hw];
    float x3 = ir[p];

    for (int s = 0; s < 6; ++s) {
        const float* __restrict__ L = ptrs[s];
        int n_ch = (s == 5) ? 3 : 4;
        x0 = fminf(fmaxf(x0, 0.f), 1.f);
        x1 = fminf(fmaxf(x1, 0.f), 1.f);
        x2 = fminf(fmaxf(x2, 0.f), 1.f);
        x3 = fminf(fmaxf(x3, 0.f), 1.f);
        float xs0 = x0 * 16.f;
        float xs1 = x1 * 16.f;
        float xs2 = x2 * 16.f;
        float xs3 = x3 * 16.f;
        int i0 = (int)xs0; i0 = i0 > 15 ? 15 : i0;
        int i1 = (int)xs1; i1 = i1 > 15 ? 15 : i1;
        int i2 = (int)xs2; i2 = i2 > 15 ? 15 : i2;
        int i3 = (int)xs3; i3 = i3 > 15 ? 15 : i3;
        float f0 = xs0 - (float)i0;
        float f1 = xs1 - (float)i1;
        float f2 = xs2 - (float)i2;
        float f3 = xs3 - (float)i3;
        float g0 = 1.f - f0;
        float g1 = 1.f - f1;
        float g2 = 1.f - f2;
        float g3 = 1.f - f3;
        float w01[4] = { g0 * g1, f0 * g1, g0 * f1, f0 * f1 };
        int off = i0 * 4913 + i1 * 289 + i2 * 17 + i3;
        float a0 = 0.f, a1 = 0.f, a2 = 0.f, a3 = 0.f;
        for (int cr = 0; cr < 16; ++cr) {
            int hi = cr >> 3, c = cr & 7;
            int idx = off + (c & 1) * 4913 + ((c >> 1) & 1) * 289 + (c >> 2) * 17 + hi;
            float w012 = w01[c & 3] * ((c >> 2) ? f2 : g2);
            float w    = w012 * (hi ? f3 : g3);
            float v0 = L[idx];
            float v1 = L[D4 + idx];
            float v2 = L[2 * D4 + idx];
            float v3 = (n_ch == 4) ? L[3 * D4 + idx] : 0.f;
            if (cr == 0) {
                a0 = v0 * w; a1 = v1 * w; a2 = v2 * w; a3 = v3 * w;
            } else {
                a0 = a0 + v0 * w; a1 = a1 + v1 * w;
                a2 = a2 + v2 * w; a3 = a3 + v3 * w;
            }
        }
        x0 = a0; x1 = a1; x2 = a2; x3 = a3;
    }

    out[vbase + hw]          = x0;
    out[vbase + HW + hw]     = x1;
    out[vbase + 2 * HW + hw] = x2;
}

extern "C" void kernel_launch(void* const* d_in, const int* in_sizes, int n_in,
                              void* d_out, int out_size, void* d_ws, size_t ws_size,
                              hipStream_t stream) {
    const float* vi = (const float*)d_in[0];
    const float* ir = (const float*)d_in[1];
    const float* raw[6] = {
        (const float*)d_in[2], (const float*)d_in[3],
        (const float*)d_in[4], (const float*)d_in[5],
        (const float*)d_in[6], (const float*)d_in[7]
    };
    float* out = (float*)d_out;

    const size_t QSZ      = (size_t)QREC * 64;               // 4,734,976 B/LUT
    const size_t NEED_Q   = 6 * QSZ;                         // ~28.4 MB
    const size_t NEED_LIN = (size_t)6 * D4 * sizeof(float4); // ~8.0 MB

    if (ws_size >= NEED_Q) {
        char* ws = (char*)d_ws;
        int pack_blocks = (QREC + 255) / 256;
        for (int s = 0; s < 6; ++s) {
            pack_quad<<<pack_blocks, 256, 0, stream>>>(raw[s], (s == 5) ? 3 : 4,
                                                       (float4*)(ws + s * QSZ));
        }
        fused_coop<<<NPIX / CBLK, CBLK, 0, stream>>>(vi, ir, (const float4*)ws, out);
    } else if (ws_size >= NEED_LIN) {
        float4* packed = (float4*)d_ws;
        int pack_blocks = (D4 + 255) / 256;
        for (int s = 0; s < 6; ++s) {
            pack_kernel<<<pack_blocks, 256, 0, stream>>>(raw[s], (s == 5) ? 3 : 4,
                                                         packed + (size_t)s * D4);
        }
        fused_mlp<<<NPIX / 256, 256, 0, stream>>>(vi, ir, packed, out);
    } else {
        fused_fallback<<<NPIX / 256, 256, 0, stream>>>(vi, ir, raw[0], raw[1], raw[2],
                                                       raw[3], raw[4], raw[5], out);
    }
}

// Round 2
// 471.360 us; speedup vs baseline: 1.1459x; 1.1459x over previous
//
#include <hip/hip_runtime.h>

// CRITICAL: bit-exact replication of the numpy fp32 oracle requires NO FMA
// contraction (hipcc default -ffp-contract=fast-honor-pragmas would fuse).
#pragma clang fp contract(off)

#define D4    83521      // 17^4 entries per LUT (per channel)
#define HW    262144     // 512*512
#define NPIX  2097152    // 8*512*512
#define CBLK  64         // cooperative kernel: single-wave blocks

// ---------- linear float4 packing: entry e holds 4 channels of e ------------
// Layout per LUT: float4[D4], index = i0*4913 + i1*289 + i2*17 + i3.
// Total 6 LUTs = 8.0 MB -> ONE stage = 1.336 MB, fully L2-resident per XCD.
__global__ __launch_bounds__(256) void pack_kernel(const float* __restrict__ src,
                                                   int n_ch,
                                                   float4* __restrict__ dst) {
    int e = blockIdx.x * 256 + threadIdx.x;
    if (e >= D4) return;
    float4 v;
    v.x = src[e];
    v.y = src[D4 + e];
    v.z = src[2 * D4 + e];
    v.w = (n_ch == 4) ? src[3 * D4 + e] : 0.f;
    dst[e] = v;
}

// Cooperative fused 6-stage chain — BARRIER-FREE (r13 structure, r15 layout).
// r13 (quad records, 4.73 MB/stage) was latency-bound on L3: random 64 B
// gathers missed the 4 MB XCD L2 (FETCH 675 MB @ ~600-900 cy). r14's
// two-phase exchange broke the 16-deep load batch (VGPR 68->60, loads
// serialized, 451 us). r15: keep r13's single-phase structure VERBATIM and
// move the gather to the LINEAR float4 layout (1.336 MB/stage, L2-resident).
// Lane kidx's corner bits are unchanged (b0=(k>>2)&1, b1=(k>>3)&1, b2=k&1,
// b3=(k>>1)&1), so the exchange mapping and the sequential accumulation are
// bit-identical to r13 (absmax 0.0 there). Only the load address changes:
// v[t] = lut[s*D4 + delta(kidx) + off(pixel)], off = i0*4913+i1*289+i2*17+i3.
// Coalescing: per pixel 8 contiguous 32 B pairs (b3 adjacent) instead of
// 4x64 B records — more segments, but every one an L2 hit.
__global__ __launch_bounds__(CBLK) void fused_coop(const float* __restrict__ vi,
                                                   const float* __restrict__ ir,
                                                   const float4* __restrict__ luts,
                                                   float* __restrict__ out) {
#pragma clang fp contract(off)
    __shared__ float4 exch[CBLK * 17];  // 272 B per pixel (17-float4 rows, conflict-free)

    int tid = threadIdx.x;              // == lane (single-wave block)
    int p = blockIdx.x * CBLK + tid;
    int b  = p >> 18;                   // HW = 2^18
    int hw = p & (HW - 1);
    int vbase = (b * 3) << 18;

    float x0 = vi[vbase + hw];
    float x1 = vi[vbase + HW + hw];
    float x2 = vi[vbase + 2 * HW + hw];
    float x3 = ir[p];

    int sub  = tid >> 4;                // which pixel of each 4-px group
    int kidx = tid & 15;                // corner code this lane loads
    // corner bits of kidx (matches accumulate's k = 4*b0 + 8*b1 + b2 + 2*b3)
    int delta = ((kidx >> 2) & 1) * 4913 + ((kidx >> 3) & 1) * 289 +
                (kidx & 1) * 17 + ((kidx >> 1) & 1);

    for (int s = 0; s < 6; ++s) {
        // per-lane LUT base folds in the corner offset (addr calc once)
        const float4* __restrict__ lutS = luts + (size_t)s * D4 + delta;

        // ---- owner: indices + weights (exact round-6 arithmetic) ----
        x0 = fminf(fmaxf(x0, 0.f), 1.f);
        x1 = fminf(fmaxf(x1, 0.f), 1.f);
        x2 = fminf(fmaxf(x2, 0.f), 1.f);
        x3 = fminf(fmaxf(x3, 0.f), 1.f);
        float xs0 = x0 * 16.f;
        float xs1 = x1 * 16.f;
        float xs2 = x2 * 16.f;
        float xs3 = x3 * 16.f;
        int i0 = (int)xs0; i0 = i0 > 15 ? 15 : i0;
        int i1 = (int)xs1; i1 = i1 > 15 ? 15 : i1;
        int i2 = (int)xs2; i2 = i2 > 15 ? 15 : i2;
        int i3 = (int)xs3; i3 = i3 > 15 ? 15 : i3;
        float f0 = xs0 - (float)i0;     // mul-then-sub, contraction OFF
        float f1 = xs1 - (float)i1;
        float f2 = xs2 - (float)i2;
        float f3 = xs3 - (float)i3;
        float g0 = 1.f - f0;
        float g1 = 1.f - f1;
        float g2 = 1.f - f2;
        float g3 = 1.f - f3;
        float w01[4] = { g0 * g1, f0 * g1, g0 * f1, f0 * f1 };

        int r00 = i0 * 4913 + i1 * 289 + i2 * 17 + i3;   // linear float4 index

        // ---- r00 exchange: pure in-wave shuffle, no LDS / no barrier ----
        int r0s[16];
#pragma unroll
        for (int t = 0; t < 16; ++t)
            r0s[t] = __shfl(r00, 4 * t + sub, 64);

        // ---- cooperative gather: 16 loads/lane, L2-resident stage LUT ----
        float4 v[16];
#pragma unroll
        for (int t = 0; t < 16; ++t)
            v[t] = lutS[r0s[t]];
        __builtin_amdgcn_sched_barrier(0);   // keep the 16-deep load batch intact

        // ---- in-wave fragment exchange (DS ops in order per wave) ----
#pragma unroll
        for (int t = 0; t < 16; ++t)
            exch[(4 * t + sub) * 17 + kidx] = v[t];
        __builtin_amdgcn_sched_barrier(0);   // pin write->read program order

        // ---- owner: exact round-6 sequential accumulation ----
        const float4* myb = &exch[tid * 17];
        float a0 = 0.f, a1 = 0.f, a2 = 0.f, a3 = 0.f;
#pragma unroll
        for (int hi = 0; hi < 2; ++hi) {     // b3
            float w3 = hi ? f3 : g3;
#pragma unroll
            for (int c = 0; c < 8; ++c) {    // b0=c&1, b1=(c>>1)&1, b2=c>>2
                int k = ((c & 3) << 2) + ((c >> 2) + 2 * hi);  // 4b0+8b1+b2+2b3
                float4 vv = myb[k];
                float w012 = w01[c & 3] * ((c >> 2) ? f2 : g2);
                float w    = w012 * w3;
                if (hi == 0 && c == 0) {
                    a0 = vv.x * w; a1 = vv.y * w; a2 = vv.z * w; a3 = vv.w * w;
                } else {
                    a0 = a0 + vv.x * w; a1 = a1 + vv.y * w;
                    a2 = a2 + vv.z * w; a3 = a3 + vv.w * w;
                }
            }
        }
        __builtin_amdgcn_sched_barrier(0);   // reads done before next stage's writes
        x0 = a0; x1 = a1; x2 = a2; x3 = a3;
    }

    out[vbase + hw]          = x0;
    out[vbase + HW + hw]     = x1;
    out[vbase + 2 * HW + hw] = x2;
}

// ---------- raw fallback (no workspace) -------------------------------------
__global__ __launch_bounds__(256) void fused_fallback(const float* __restrict__ vi,
                                                      const float* __restrict__ ir,
                                                      const float* __restrict__ l8,
                                                      const float* __restrict__ l00,
                                                      const float* __restrict__ l01,
                                                      const float* __restrict__ l02,
                                                      const float* __restrict__ l03,
                                                      const float* __restrict__ lpgf,
                                                      float* __restrict__ out) {
#pragma clang fp contract(off)
    int p = blockIdx.x * 256 + threadIdx.x;
    if (p >= NPIX) return;
    int b  = p >> 18;
    int hw = p & (HW - 1);
    int vbase = (b * 3) << 18;

    const float* ptrs[6] = { l8, l00, l01, l02, l03, lpgf };

    float x0 = vi[vbase + hw];
    float x1 = vi[vbase + HW + hw];
    float x2 = vi[vbase + 2 * HW + hw];
    float x3 = ir[p];

    for (int s = 0; s < 6; ++s) {
        const float* __restrict__ L = ptrs[s];
        int n_ch = (s == 5) ? 3 : 4;
        x0 = fminf(fmaxf(x0, 0.f), 1.f);
        x1 = fminf(fmaxf(x1, 0.f), 1.f);
        x2 = fminf(fmaxf(x2, 0.f), 1.f);
        x3 = fminf(fmaxf(x3, 0.f), 1.f);
        float xs0 = x0 * 16.f;
        float xs1 = x1 * 16.f;
        float xs2 = x2 * 16.f;
        float xs3 = x3 * 16.f;
        int i0 = (int)xs0; i0 = i0 > 15 ? 15 : i0;
        int i1 = (int)xs1; i1 = i1 > 15 ? 15 : i1;
        int i2 = (int)xs2; i2 = i2 > 15 ? 15 : i2;
        int i3 = (int)xs3; i3 = i3 > 15 ? 15 : i3;
        float f0 = xs0 - (float)i0;
        float f1 = xs1 - (float)i1;
        float f2 = xs2 - (float)i2;
        float f3 = xs3 - (float)i3;
        float g0 = 1.f - f0;
        float g1 = 1.f - f1;
        float g2 = 1.f - f2;
        float g3 = 1.f - f3;
        float w01[4] = { g0 * g1, f0 * g1, g0 * f1, f0 * f1 };
        int off = i0 * 4913 + i1 * 289 + i2 * 17 + i3;
        float a0 = 0.f, a1 = 0.f, a2 = 0.f, a3 = 0.f;
        for (int cr = 0; cr < 16; ++cr) {
            int hi = cr >> 3, c = cr & 7;
            int idx = off + (c & 1) * 4913 + ((c >> 1) & 1) * 289 + (c >> 2) * 17 + hi;
            float w012 = w01[c & 3] * ((c >> 2) ? f2 : g2);
            float w    = w012 * (hi ? f3 : g3);
            float v0 = L[idx];
            float v1 = L[D4 + idx];
            float v2 = L[2 * D4 + idx];
            float v3 = (n_ch == 4) ? L[3 * D4 + idx] : 0.f;
            if (cr == 0) {
                a0 = v0 * w; a1 = v1 * w; a2 = v2 * w; a3 = v3 * w;
            } else {
                a0 = a0 + v0 * w; a1 = a1 + v1 * w;
                a2 = a2 + v2 * w; a3 = a3 + v3 * w;
            }
        }
        x0 = a0; x1 = a1; x2 = a2; x3 = a3;
    }

    out[vbase + hw]          = x0;
    out[vbase + HW + hw]     = x1;
    out[vbase + 2 * HW + hw] = x2;
}

extern "C" void kernel_launch(void* const* d_in, const int* in_sizes, int n_in,
                              void* d_out, int out_size, void* d_ws, size_t ws_size,
                              hipStream_t stream) {
    const float* vi = (const float*)d_in[0];
    const float* ir = (const float*)d_in[1];
    const float* raw[6] = {
        (const float*)d_in[2], (const float*)d_in[3],
        (const float*)d_in[4], (const float*)d_in[5],
        (const float*)d_in[6], (const float*)d_in[7]
    };
    float* out = (float*)d_out;

    const size_t NEED_LIN = (size_t)6 * D4 * sizeof(float4); // ~8.0 MB

    if (ws_size >= NEED_LIN) {
        float4* packed = (float4*)d_ws;
        int pack_blocks = (D4 + 255) / 256;
        for (int s = 0; s < 6; ++s) {
            pack_kernel<<<pack_blocks, 256, 0, stream>>>(raw[s], (s == 5) ? 3 : 4,
                                                         packed + (size_t)s * D4);
        }
        fused_coop<<<NPIX / CBLK, CBLK, 0, stream>>>(vi, ir, (const float4*)packed, out);
    } else {
        fused_fallback<<<NPIX / 256, 256, 0, stream>>>(vi, ir, raw[0], raw[1], raw[2],
                                                       raw[3], raw[4], raw[5], out);
    }
}

// Round 3
// 382.739 us; speedup vs baseline: 1.4112x; 1.2315x over previous
//
#include <hip/hip_runtime.h>

// CRITICAL: bit-exact replication of the numpy fp32 oracle requires NO FMA
// contraction (hipcc default -ffp-contract=fast-honor-pragmas would fuse).
#pragma clang fp contract(off)

#define D4    83521      // 17^4 entries per LUT (per channel)
#define HW    262144     // 512*512
#define NPIX  2097152    // 8*512*512
#define QREC  73984      // 17*17*16*16 quad records per LUT (64 B each)
#define CBLK  64         // cooperative kernel: single-wave blocks

// ---------- quad packing: one 64 B record = 2x2 (i2,i3) corner block --------
// Record r = ((i0*17 + i1)*16 + i2)*16 + i3 (i2,i3 in [0,16)); slot g holds
// channels of corner (i2+(g&1), i3+(g>>1)). Verified bit-exact (r7/r11/r12).
__global__ __launch_bounds__(256) void pack_quad(const float* __restrict__ src,
                                                 int n_ch,
                                                 float4* __restrict__ dst) {
    int e = blockIdx.x * 256 + threadIdx.x;
    if (e >= QREC) return;
    int i3 = e & 15;
    int i2 = (e >> 4) & 15;
    int t  = e >> 8;              // i0*17 + i1
    int i0 = t / 17;
    int i1 = t - i0 * 17;
    int base = i0 * 4913 + i1 * 289 + i2 * 17 + i3;
    float4* rec = dst + (size_t)e * 4;
#pragma unroll
    for (int g = 0; g < 4; ++g) {
        int o = base + (g & 1) * 17 + (g >> 1);
        float4 v;
        v.x = src[o];
        v.y = src[D4 + o];
        v.z = src[2 * D4 + o];
        v.w = (n_ch == 4) ? src[3 * D4 + o] : 0.f;
        rec[g] = v;
    }
}

// Cooperative fused 6-stage chain — BARRIER-FREE (r13 structure).
// r16 change vs r13: __launch_bounds__(CBLK, 2) instead of (CBLK).
// Diagnosis: r13's VGPR=68 cannot hold the 16-deep float4 load batch
// (64 VGPRs of payload alone) -> compiler split the batch and drained
// vmcnt mid-stage -> per-stage latency ~8K cycles (2-deep pipelining of
// ~900 cy L3 round trips; 285 us). min-waves/EU=2 grants up to 256 VGPR
// so the whole batch issues before any wait: per-stage latency ~= one
// round trip. LDS (17408 B -> 9 blocks/CU) still provides 9 resident
// waves = 144 outstanding loads/CU to cover the TA-issue floor.
// r14 taught us NOT to restructure the exchange (broke the batch);
// r15 taught us the quad layout's 16x64B aligned segments/instr beats
// the linear layout's ~32x32B (TA-serialization), even from L3.
// Arithmetic + exchange mapping verbatim r12/r13 (bit-exact, absmax 0.0).
__global__ __launch_bounds__(CBLK, 2) void fused_coop(const float* __restrict__ vi,
                                                      const float* __restrict__ ir,
                                                      const float4* __restrict__ luts,
                                                      float* __restrict__ out) {
#pragma clang fp contract(off)
    __shared__ float4 exch[CBLK * 17];  // 272 B per pixel (17-float4 rows, conflict-free)

    int tid = threadIdx.x;              // == lane (single-wave block)
    int p = blockIdx.x * CBLK + tid;
    int b  = p >> 18;                   // HW = 2^18
    int hw = p & (HW - 1);
    int vbase = (b * 3) << 18;

    float x0 = vi[vbase + hw];
    float x1 = vi[vbase + HW + hw];
    float x2 = vi[vbase + 2 * HW + hw];
    float x3 = ir[p];

    int rec     = (tid >> 2) & 3;       // loader role, fixed per lane
    int slot    = tid & 3;
    int rec_off = ((rec & 1) ? 4352 : 0) + ((rec & 2) ? 256 : 0);
    int sub     = tid >> 4;             // which pixel of each 4-px group
    int kidx    = tid & 15;             // rec*4 + slot

    for (int s = 0; s < 6; ++s) {
        // per-lane LUT base folds in the role offset (addr calc once)
        const float4* __restrict__ lutS =
            luts + (size_t)s * QREC * 4 + (size_t)rec_off * 4 + slot;

        // ---- owner: indices + weights (exact round-6 arithmetic) ----
        x0 = fminf(fmaxf(x0, 0.f), 1.f);
        x1 = fminf(fmaxf(x1, 0.f), 1.f);
        x2 = fminf(fmaxf(x2, 0.f), 1.f);
        x3 = fminf(fmaxf(x3, 0.f), 1.f);
        float xs0 = x0 * 16.f;
        float xs1 = x1 * 16.f;
        float xs2 = x2 * 16.f;
        float xs3 = x3 * 16.f;
        int i0 = (int)xs0; i0 = i0 > 15 ? 15 : i0;
        int i1 = (int)xs1; i1 = i1 > 15 ? 15 : i1;
        int i2 = (int)xs2; i2 = i2 > 15 ? 15 : i2;
        int i3 = (int)xs3; i3 = i3 > 15 ? 15 : i3;
        float f0 = xs0 - (float)i0;     // mul-then-sub, contraction OFF
        float f1 = xs1 - (float)i1;
        float f2 = xs2 - (float)i2;
        float f3 = xs3 - (float)i3;
        float g0 = 1.f - f0;
        float g1 = 1.f - f1;
        float g2 = 1.f - f2;
        float g3 = 1.f - f3;
        float w01[4] = { g0 * g1, f0 * g1, g0 * f1, f0 * f1 };

        int r00 = ((i0 * 17 + i1) * 16 + i2) * 16 + i3;

        // ---- r00 exchange: pure in-wave shuffle, no LDS / no barrier ----
        int r0s[16];
#pragma unroll
        for (int t = 0; t < 16; ++t)
            r0s[t] = __shfl(r00, 4 * t + sub, 64);

        // ---- cooperative gather: 16 loads/lane, 16 coalesced trans/instr ----
        float4 v[16];
#pragma unroll
        for (int t = 0; t < 16; ++t)
            v[t] = lutS[(size_t)r0s[t] * 4];
        __builtin_amdgcn_sched_barrier(0);   // keep the 16-deep load batch intact

        // ---- in-wave fragment exchange (DS ops in order per wave) ----
#pragma unroll
        for (int t = 0; t < 16; ++t)
            exch[(4 * t + sub) * 17 + kidx] = v[t];
        __builtin_amdgcn_sched_barrier(0);   // pin write->read program order

        // ---- owner: exact round-6 sequential accumulation ----
        const float4* myb = &exch[tid * 17];
        float a0 = 0.f, a1 = 0.f, a2 = 0.f, a3 = 0.f;
#pragma unroll
        for (int hi = 0; hi < 2; ++hi) {     // b3
            float w3 = hi ? f3 : g3;
#pragma unroll
            for (int c = 0; c < 8; ++c) {    // b0=c&1, b1=(c>>1)&1, b2=c>>2
                int k = ((c & 3) << 2) + ((c >> 2) + 2 * hi);  // rec*4 + slot
                float4 vv = myb[k];
                float w012 = w01[c & 3] * ((c >> 2) ? f2 : g2);
                float w    = w012 * w3;
                if (hi == 0 && c == 0) {
                    a0 = vv.x * w; a1 = vv.y * w; a2 = vv.z * w; a3 = vv.w * w;
                } else {
                    a0 = a0 + vv.x * w; a1 = a1 + vv.y * w;
                    a2 = a2 + vv.z * w; a3 = a3 + vv.w * w;
                }
            }
        }
        __builtin_amdgcn_sched_barrier(0);   // reads done before next stage's writes
        x0 = a0; x1 = a1; x2 = a2; x3 = a3;
    }

    out[vbase + hw]          = x0;
    out[vbase + HW + hw]     = x1;
    out[vbase + 2 * HW + hw] = x2;
}

// ---------- middle tier: round-10 fused kernel (proven, 653 us) -------------
__global__ __launch_bounds__(256) void pack_kernel(const float* __restrict__ src,
                                                   int n_ch,
                                                   float4* __restrict__ dst) {
    int e = blockIdx.x * 256 + threadIdx.x;
    if (e >= D4) return;
    float4 v;
    v.x = src[e];
    v.y = src[D4 + e];
    v.z = src[2 * D4 + e];
    v.w = (n_ch == 4) ? src[3 * D4 + e] : 0.f;
    dst[e] = v;
}

__global__ __launch_bounds__(256) void fused_mlp(const float* __restrict__ vi,
                                                 const float* __restrict__ ir,
                                                 const float4* __restrict__ luts,
                                                 float* __restrict__ out) {
#pragma clang fp contract(off)
    int p = blockIdx.x * 256 + threadIdx.x;
    if (p >= NPIX) return;
    int b  = p >> 18;
    int hw = p & (HW - 1);
    int vbase = (b * 3) << 18;

    float x0 = vi[vbase + hw];
    float x1 = vi[vbase + HW + hw];
    float x2 = vi[vbase + 2 * HW + hw];
    float x3 = ir[p];

    for (int s = 0; s < 6; ++s) {
        const float4* __restrict__ lut = luts + (size_t)s * D4;
        x0 = fminf(fmaxf(x0, 0.f), 1.f);
        x1 = fminf(fmaxf(x1, 0.f), 1.f);
        x2 = fminf(fmaxf(x2, 0.f), 1.f);
        x3 = fminf(fmaxf(x3, 0.f), 1.f);
        float xs0 = x0 * 16.f;
        float xs1 = x1 * 16.f;
        float xs2 = x2 * 16.f;
        float xs3 = x3 * 16.f;
        int i0 = (int)xs0; i0 = i0 > 15 ? 15 : i0;
        int i1 = (int)xs1; i1 = i1 > 15 ? 15 : i1;
        int i2 = (int)xs2; i2 = i2 > 15 ? 15 : i2;
        int i3 = (int)xs3; i3 = i3 > 15 ? 15 : i3;
        float f0 = xs0 - (float)i0;
        float f1 = xs1 - (float)i1;
        float f2 = xs2 - (float)i2;
        float f3 = xs3 - (float)i3;
        float g0 = 1.f - f0;
        float g1 = 1.f - f1;
        float g2 = 1.f - f2;
        float g3 = 1.f - f3;
        float w01[4] = { g0 * g1, f0 * g1, g0 * f1, f0 * f1 };
        int off = i0 * 4913 + i1 * 289 + i2 * 17 + i3;

        float4 v[16];
#pragma unroll
        for (int hi = 0; hi < 2; ++hi) {
#pragma unroll
            for (int c = 0; c < 8; ++c) {
                int d = (c & 1) * 4913 + ((c >> 1) & 1) * 289 + (c >> 2) * 17 + hi;
                v[hi * 8 + c] = lut[off + d];
            }
        }
        __builtin_amdgcn_sched_barrier(0);

        float a0 = 0.f, a1 = 0.f, a2 = 0.f, a3 = 0.f;
#pragma unroll
        for (int hi = 0; hi < 2; ++hi) {
            float w3 = hi ? f3 : g3;
#pragma unroll
            for (int c = 0; c < 8; ++c) {
                float4 vv = v[hi * 8 + c];
                float w012 = w01[c & 3] * ((c >> 2) ? f2 : g2);
                float w    = w012 * w3;
                if (hi == 0 && c == 0) {
                    a0 = vv.x * w; a1 = vv.y * w; a2 = vv.z * w; a3 = vv.w * w;
                } else {
                    a0 = a0 + vv.x * w; a1 = a1 + vv.y * w;
                    a2 = a2 + vv.z * w; a3 = a3 + vv.w * w;
                }
            }
        }
        x0 = a0; x1 = a1; x2 = a2; x3 = a3;
    }

    out[vbase + hw]          = x0;
    out[vbase + HW + hw]     = x1;
    out[vbase + 2 * HW + hw] = x2;
}

// ---------- raw fallback (no workspace) -------------------------------------
__global__ __launch_bounds__(256) void fused_fallback(const float* __restrict__ vi,
                                                      const float* __restrict__ ir,
                                                      const float* __restrict__ l8,
                                                      const float* __restrict__ l00,
                                                      const float* __restrict__ l01,
                                                      const float* __restrict__ l02,
                                                      const float* __restrict__ l03,
                                                      const float* __restrict__ lpgf,
                                                      float* __restrict__ out) {
#pragma clang fp contract(off)
    int p = blockIdx.x * 256 + threadIdx.x;
    if (p >= NPIX) return;
    int b  = p >> 18;
    int hw = p & (HW - 1);
    int vbase = (b * 3) << 18;

    const float* ptrs[6] = { l8, l00, l01, l02, l03, lpgf };

    float x0 = vi[vbase + hw];
    float x1 = vi[vbase + HW + hw];
    float x2 = vi[vbase + 2 * HW + hw];
    float x3 = ir[p];

    for (int s = 0; s < 6; ++s) {
        const float* __restrict__ L = ptrs[s];
        int n_ch = (s == 5) ? 3 : 4;
        x0 = fminf(fmaxf(x0, 0.f), 1.f);
        x1 = fminf(fmaxf(x1, 0.f), 1.f);
        x2 = fminf(fmaxf(x2, 0.f), 1.f);
        x3 = fminf(fmaxf(x3, 0.f), 1.f);
        float xs0 = x0 * 16.f;
        float xs1 = x1 * 16.f;
        float xs2 = x2 * 16.f;
        float xs3 = x3 * 16.f;
        int i0 = (int)xs0; i0 = i0 > 15 ? 15 : i0;
        int i1 = (int)xs1; i1 = i1 > 15 ? 15 : i1;
        int i2 = (int)xs2; i2 = i2 > 15 ? 15 : i2;
        int i3 = (int)xs3; i3 = i3 > 15 ? 15 : i3;
        float f0 = xs0 - (float)i0;
        float f1 = xs1 - (float)i1;
        float f2 = xs2 - (float)i2;
        float f3 = xs3 - (float)i3;
        float g0 = 1.f - f0;
        float g1 = 1.f - f1;
        float g2 = 1.f - f2;
        float g3 = 1.f - f3;
        float w01[4] = { g0 * g1, f0 * g1, g0 * f1, f0 * f1 };
        int off = i0 * 4913 + i1 * 289 + i2 * 17 + i3;
        float a0 = 0.f, a1 = 0.f, a2 = 0.f, a3 = 0.f;
        for (int cr = 0; cr < 16; ++cr) {
            int hi = cr >> 3, c = cr & 7;
            int idx = off + (c & 1) * 4913 + ((c >> 1) & 1) * 289 + (c >> 2) * 17 + hi;
            float w012 = w01[c & 3] * ((c >> 2) ? f2 : g2);
            float w    = w012 * (hi ? f3 : g3);
            float v0 = L[idx];
            float v1 = L[D4 + idx];
            float v2 = L[2 * D4 + idx];
            float v3 = (n_ch == 4) ? L[3 * D4 + idx] : 0.f;
            if (cr == 0) {
                a0 = v0 * w; a1 = v1 * w; a2 = v2 * w; a3 = v3 * w;
            } else {
                a0 = a0 + v0 * w; a1 = a1 + v1 * w;
                a2 = a2 + v2 * w; a3 = a3 + v3 * w;
            }
        }
        x0 = a0; x1 = a1; x2 = a2; x3 = a3;
    }

    out[vbase + hw]          = x0;
    out[vbase + HW + hw]     = x1;
    out[vbase + 2 * HW + hw] = x2;
}

extern "C" void kernel_launch(void* const* d_in, const int* in_sizes, int n_in,
                              void* d_out, int out_size, void* d_ws, size_t ws_size,
                              hipStream_t stream) {
    const float* vi = (const float*)d_in[0];
    const float* ir = (const float*)d_in[1];
    const float* raw[6] = {
        (const float*)d_in[2], (const float*)d_in[3],
        (const float*)d_in[4], (const float*)d_in[5],
        (const float*)d_in[6], (const float*)d_in[7]
    };
    float* out = (float*)d_out;

    const size_t QSZ      = (size_t)QREC * 64;               // 4,734,976 B/LUT
    const size_t NEED_Q   = 6 * QSZ;                         // ~28.4 MB
    const size_t NEED_LIN = (size_t)6 * D4 * sizeof(float4); // ~8.0 MB

    if (ws_size >= NEED_Q) {
        char* ws = (char*)d_ws;
        int pack_blocks = (QREC + 255) / 256;
        for (int s = 0; s < 6; ++s) {
            pack_quad<<<pack_blocks, 256, 0, stream>>>(raw[s], (s == 5) ? 3 : 4,
                                                       (float4*)(ws + s * QSZ));
        }
        fused_coop<<<NPIX / CBLK, CBLK, 0, stream>>>(vi, ir, (const float4*)ws, out);
    } else if (ws_size >= NEED_LIN) {
        float4* packed = (float4*)d_ws;
        int pack_blocks = (D4 + 255) / 256;
        for (int s = 0; s < 6; ++s) {
            pack_kernel<<<pack_blocks, 256, 0, stream>>>(raw[s], (s == 5) ? 3 : 4,
                                                         packed + (size_t)s * D4);
        }
        fused_mlp<<<NPIX / 256, 256, 0, stream>>>(vi, ir, packed, out);
    } else {
        fused_fallback<<<NPIX / 256, 256, 0, stream>>>(vi, ir, raw[0], raw[1], raw[2],
                                                       raw[3], raw[4], raw[5], out);
    }
}

// Round 4
// 291.558 us; speedup vs baseline: 1.8526x; 1.3127x over previous
//
#include <hip/hip_runtime.h>

// CRITICAL: bit-exact replication of the numpy fp32 oracle requires NO FMA
// contraction (hipcc default -ffp-contract=fast-honor-pragmas would fuse).
#pragma clang fp contract(off)

#define D4    83521      // 17^4 entries per LUT (per channel)
#define HW    262144     // 512*512
#define NPIX  2097152    // 8*512*512
#define QREC  73984      // 17*17*16*16 quad records per LUT (64 B each)
#define RECN  69632      // 17*16*16*16 oct records per LUT (128 B each)
#define CBLK  64         // cooperative kernel: single-wave blocks

// ---------- oct packing: one 128 B record = 2x2x2 (i1,i2,i3) corner block ---
// Record e = ((i0*16 + i1)*16 + i2)*16 + i3 (i1,i2,i3 in [0,16), i0 in [0,17));
// slot g (float4) holds channels of corner (i1+((g>>2)&1), i2+((g>>1)&1),
// i3+(g&1)). A pixel's 16 corners = records R(i0) and R(i0)+4096 (i0+1),
// each ONE aligned 128 B line. One float4 slot per thread -> coalesced writes.
__global__ __launch_bounds__(256) void pack_oct(const float* __restrict__ src,
                                                int n_ch,
                                                float4* __restrict__ dst) {
    int j = blockIdx.x * 256 + threadIdx.x;   // one float4 slot per thread
    if (j >= RECN * 8) return;
    int g = j & 7;                            // slot = b1*4 + b2*2 + b3
    int e = j >> 3;                           // record index
    int i3 = e & 15;
    int i2 = (e >> 4) & 15;
    int i1 = (e >> 8) & 15;
    int i0 = e >> 12;                         // [0,17)
    int o = i0 * 4913 + i1 * 289 + i2 * 17 + i3
          + ((g >> 2) & 1) * 289 + ((g >> 1) & 1) * 17 + (g & 1);
    float4 v;
    v.x = src[o];
    v.y = src[D4 + o];
    v.z = src[2 * D4 + o];
    v.w = (n_ch == 4) ? src[3 * D4 + o] : 0.f;
    dst[j] = v;                               // fully coalesced 16 B/lane
}

// Cooperative fused 6-stage chain — BARRIER-FREE (r13 structure, OCT layout).
// Evidence r13 vs r15: the limiter is cache-LINE transactions through TA/L1
// (~3.5 cy/line), not cache level or bytes (L2-resident linear layout was
// SLOWER at 32x32B segs/instr; quad 16x64B = 285 us). r17: oct records give
// 8x128B lines/instr — 2 lines per pixel per stage, the floor for a 256 B
// corner set, with 100% consumption of every fetched line.
// Lane kidx's corner bits and the exchange/accumulate are VERBATIM r13
// (bit-exact, absmax 0.0); only the load address changes.
__global__ __launch_bounds__(CBLK) void fused_coop(const float* __restrict__ vi,
                                                   const float* __restrict__ ir,
                                                   const float4* __restrict__ luts,
                                                   float* __restrict__ out) {
#pragma clang fp contract(off)
    __shared__ float4 exch[CBLK * 17];  // 272 B per pixel (17-float4 rows, conflict-free)

    int tid = threadIdx.x;              // == lane (single-wave block)
    int p = blockIdx.x * CBLK + tid;
    int b  = p >> 18;                   // HW = 2^18
    int hw = p & (HW - 1);
    int vbase = (b * 3) << 18;

    float x0 = vi[vbase + hw];
    float x1 = vi[vbase + HW + hw];
    float x2 = vi[vbase + 2 * HW + hw];
    float x3 = ir[p];

    int sub  = tid >> 4;                // which pixel of each 4-px group
    int kidx = tid & 15;                // corner code: b0=(k>>2)&1, b1=(k>>3)&1,
                                        //              b2=k&1,      b3=(k>>1)&1
    int b0   = (kidx >> 2) & 1;
    int slot = ((kidx >> 3) & 1) * 4 + (kidx & 1) * 2 + ((kidx >> 1) & 1);

    for (int s = 0; s < 6; ++s) {
        // per-lane LUT base folds in i0-record select + slot (addr calc once)
        const float4* __restrict__ lutS =
            luts + (size_t)s * (RECN * 8) + b0 * (4096 * 8) + slot;

        // ---- owner: indices + weights (exact round-6 arithmetic) ----
        x0 = fminf(fmaxf(x0, 0.f), 1.f);
        x1 = fminf(fmaxf(x1, 0.f), 1.f);
        x2 = fminf(fmaxf(x2, 0.f), 1.f);
        x3 = fminf(fmaxf(x3, 0.f), 1.f);
        float xs0 = x0 * 16.f;
        float xs1 = x1 * 16.f;
        float xs2 = x2 * 16.f;
        float xs3 = x3 * 16.f;
        int i0 = (int)xs0; i0 = i0 > 15 ? 15 : i0;
        int i1 = (int)xs1; i1 = i1 > 15 ? 15 : i1;
        int i2 = (int)xs2; i2 = i2 > 15 ? 15 : i2;
        int i3 = (int)xs3; i3 = i3 > 15 ? 15 : i3;
        float f0 = xs0 - (float)i0;     // mul-then-sub, contraction OFF
        float f1 = xs1 - (float)i1;
        float f2 = xs2 - (float)i2;
        float f3 = xs3 - (float)i3;
        float g0 = 1.f - f0;
        float g1 = 1.f - f1;
        float g2 = 1.f - f2;
        float g3 = 1.f - f3;
        float w01[4] = { g0 * g1, f0 * g1, g0 * f1, f0 * f1 };

        int r00 = ((i0 * 16 + i1) * 16 + i2) * 16 + i3;   // oct record index

        // ---- r00 exchange: pure in-wave shuffle, no LDS / no barrier ----
        int r0s[16];
#pragma unroll
        for (int t = 0; t < 16; ++t)
            r0s[t] = __shfl(r00, 4 * t + sub, 64);

        // ---- cooperative gather: 16 loads/lane, 8 x 128 B lines/instr ----
        float4 v[16];
#pragma unroll
        for (int t = 0; t < 16; ++t)
            v[t] = lutS[(size_t)r0s[t] * 8];
        __builtin_amdgcn_sched_barrier(0);   // keep the 16-deep load batch intact

        // ---- in-wave fragment exchange (DS ops in order per wave) ----
#pragma unroll
        for (int t = 0; t < 16; ++t)
            exch[(4 * t + sub) * 17 + kidx] = v[t];
        __builtin_amdgcn_sched_barrier(0);   // pin write->read program order

        // ---- owner: exact round-6 sequential accumulation ----
        const float4* myb = &exch[tid * 17];
        float a0 = 0.f, a1 = 0.f, a2 = 0.f, a3 = 0.f;
#pragma unroll
        for (int hi = 0; hi < 2; ++hi) {     // b3
            float w3 = hi ? f3 : g3;
#pragma unroll
            for (int c = 0; c < 8; ++c) {    // b0=c&1, b1=(c>>1)&1, b2=c>>2
                int k = ((c & 3) << 2) + ((c >> 2) + 2 * hi);  // 4b0+8b1+b2+2b3
                float4 vv = myb[k];
                float w012 = w01[c & 3] * ((c >> 2) ? f2 : g2);
                float w    = w012 * w3;
                if (hi == 0 && c == 0) {
                    a0 = vv.x * w; a1 = vv.y * w; a2 = vv.z * w; a3 = vv.w * w;
                } else {
                    a0 = a0 + vv.x * w; a1 = a1 + vv.y * w;
                    a2 = a2 + vv.z * w; a3 = a3 + vv.w * w;
                }
            }
        }
        __builtin_amdgcn_sched_barrier(0);   // reads done before next stage's writes
        x0 = a0; x1 = a1; x2 = a2; x3 = a3;
    }

    out[vbase + hw]          = x0;
    out[vbase + HW + hw]     = x1;
    out[vbase + 2 * HW + hw] = x2;
}

// ---------- quad tier (proven r13, 285 us coop): fallback if ws < 53.5 MB ---
__global__ __launch_bounds__(256) void pack_quad(const float* __restrict__ src,
                                                 int n_ch,
                                                 float4* __restrict__ dst) {
    int e = blockIdx.x * 256 + threadIdx.x;
    if (e >= QREC) return;
    int i3 = e & 15;
    int i2 = (e >> 4) & 15;
    int t  = e >> 8;              // i0*17 + i1
    int i0 = t / 17;
    int i1 = t - i0 * 17;
    int base = i0 * 4913 + i1 * 289 + i2 * 17 + i3;
    float4* rec = dst + (size_t)e * 4;
#pragma unroll
    for (int g = 0; g < 4; ++g) {
        int o = base + (g & 1) * 17 + (g >> 1);
        float4 v;
        v.x = src[o];
        v.y = src[D4 + o];
        v.z = src[2 * D4 + o];
        v.w = (n_ch == 4) ? src[3 * D4 + o] : 0.f;
        rec[g] = v;
    }
}

__global__ __launch_bounds__(CBLK) void fused_coop_q(const float* __restrict__ vi,
                                                     const float* __restrict__ ir,
                                                     const float4* __restrict__ luts,
                                                     float* __restrict__ out) {
#pragma clang fp contract(off)
    __shared__ float4 exch[CBLK * 17];

    int tid = threadIdx.x;
    int p = blockIdx.x * CBLK + tid;
    int b  = p >> 18;
    int hw = p & (HW - 1);
    int vbase = (b * 3) << 18;

    float x0 = vi[vbase + hw];
    float x1 = vi[vbase + HW + hw];
    float x2 = vi[vbase + 2 * HW + hw];
    float x3 = ir[p];

    int rec     = (tid >> 2) & 3;
    int slot    = tid & 3;
    int rec_off = ((rec & 1) ? 4352 : 0) + ((rec & 2) ? 256 : 0);
    int sub     = tid >> 4;
    int kidx    = tid & 15;

    for (int s = 0; s < 6; ++s) {
        const float4* __restrict__ lutS =
            luts + (size_t)s * QREC * 4 + (size_t)rec_off * 4 + slot;

        x0 = fminf(fmaxf(x0, 0.f), 1.f);
        x1 = fminf(fmaxf(x1, 0.f), 1.f);
        x2 = fminf(fmaxf(x2, 0.f), 1.f);
        x3 = fminf(fmaxf(x3, 0.f), 1.f);
        float xs0 = x0 * 16.f;
        float xs1 = x1 * 16.f;
        float xs2 = x2 * 16.f;
        float xs3 = x3 * 16.f;
        int i0 = (int)xs0; i0 = i0 > 15 ? 15 : i0;
        int i1 = (int)xs1; i1 = i1 > 15 ? 15 : i1;
        int i2 = (int)xs2; i2 = i2 > 15 ? 15 : i2;
        int i3 = (int)xs3; i3 = i3 > 15 ? 15 : i3;
        float f0 = xs0 - (float)i0;
        float f1 = xs1 - (float)i1;
        float f2 = xs2 - (float)i2;
        float f3 = xs3 - (float)i3;
        float g0 = 1.f - f0;
        float g1 = 1.f - f1;
        float g2 = 1.f - f2;
        float g3 = 1.f - f3;
        float w01[4] = { g0 * g1, f0 * g1, g0 * f1, f0 * f1 };

        int r00 = ((i0 * 17 + i1) * 16 + i2) * 16 + i3;

        int r0s[16];
#pragma unroll
        for (int t = 0; t < 16; ++t)
            r0s[t] = __shfl(r00, 4 * t + sub, 64);

        float4 v[16];
#pragma unroll
        for (int t = 0; t < 16; ++t)
            v[t] = lutS[(size_t)r0s[t] * 4];
        __builtin_amdgcn_sched_barrier(0);

#pragma unroll
        for (int t = 0; t < 16; ++t)
            exch[(4 * t + sub) * 17 + kidx] = v[t];
        __builtin_amdgcn_sched_barrier(0);

        const float4* myb = &exch[tid * 17];
        float a0 = 0.f, a1 = 0.f, a2 = 0.f, a3 = 0.f;
#pragma unroll
        for (int hi = 0; hi < 2; ++hi) {
            float w3 = hi ? f3 : g3;
#pragma unroll
            for (int c = 0; c < 8; ++c) {
                int k = ((c & 3) << 2) + ((c >> 2) + 2 * hi);
                float4 vv = myb[k];
                float w012 = w01[c & 3] * ((c >> 2) ? f2 : g2);
                float w    = w012 * w3;
                if (hi == 0 && c == 0) {
                    a0 = vv.x * w; a1 = vv.y * w; a2 = vv.z * w; a3 = vv.w * w;
                } else {
                    a0 = a0 + vv.x * w; a1 = a1 + vv.y * w;
                    a2 = a2 + vv.z * w; a3 = a3 + vv.w * w;
                }
            }
        }
        __builtin_amdgcn_sched_barrier(0);
        x0 = a0; x1 = a1; x2 = a2; x3 = a3;
    }

    out[vbase + hw]          = x0;
    out[vbase + HW + hw]     = x1;
    out[vbase + 2 * HW + hw] = x2;
}

// ---------- raw fallback (no workspace) -------------------------------------
__global__ __launch_bounds__(256) void fused_fallback(const float* __restrict__ vi,
                                                      const float* __restrict__ ir,
                                                      const float* __restrict__ l8,
                                                      const float* __restrict__ l00,
                                                      const float* __restrict__ l01,
                                                      const float* __restrict__ l02,
                                                      const float* __restrict__ l03,
                                                      const float* __restrict__ lpgf,
                                                      float* __restrict__ out) {
#pragma clang fp contract(off)
    int p = blockIdx.x * 256 + threadIdx.x;
    if (p >= NPIX) return;
    int b  = p >> 18;
    int hw = p & (HW - 1);
    int vbase = (b * 3) << 18;

    const float* ptrs[6] = { l8, l00, l01, l02, l03, lpgf };

    float x0 = vi[vbase + hw];
    float x1 = vi[vbase + HW + hw];
    float x2 = vi[vbase + 2 * HW + hw];
    float x3 = ir[p];

    for (int s = 0; s < 6; ++s) {
        const float* __restrict__ L = ptrs[s];
        int n_ch = (s == 5) ? 3 : 4;
        x0 = fminf(fmaxf(x0, 0.f), 1.f);
        x1 = fminf(fmaxf(x1, 0.f), 1.f);
        x2 = fminf(fmaxf(x2, 0.f), 1.f);
        x3 = fminf(fmaxf(x3, 0.f), 1.f);
        float xs0 = x0 * 16.f;
        float xs1 = x1 * 16.f;
        float xs2 = x2 * 16.f;
        float xs3 = x3 * 16.f;
        int i0 = (int)xs0; i0 = i0 > 15 ? 15 : i0;
        int i1 = (int)xs1; i1 = i1 > 15 ? 15 : i1;
        int i2 = (int)xs2; i2 = i2 > 15 ? 15 : i2;
        int i3 = (int)xs3; i3 = i3 > 15 ? 15 : i3;
        float f0 = xs0 - (float)i0;
        float f1 = xs1 - (float)i1;
        float f2 = xs2 - (float)i2;
        float f3 = xs3 - (float)i3;
        float g0 = 1.f - f0;
        float g1 = 1.f - f1;
        float g2 = 1.f - f2;
        float g3 = 1.f - f3;
        float w01[4] = { g0 * g1, f0 * g1, g0 * f1, f0 * f1 };
        int off = i0 * 4913 + i1 * 289 + i2 * 17 + i3;
        float a0 = 0.f, a1 = 0.f, a2 = 0.f, a3 = 0.f;
        for (int cr = 0; cr < 16; ++cr) {
            int hi = cr >> 3, c = cr & 7;
            int idx = off + (c & 1) * 4913 + ((c >> 1) & 1) * 289 + (c >> 2) * 17 + hi;
            float w012 = w01[c & 3] * ((c >> 2) ? f2 : g2);
            float w    = w012 * (hi ? f3 : g3);
            float v0 = L[idx];
            float v1 = L[D4 + idx];
            float v2 = L[2 * D4 + idx];
            float v3 = (n_ch == 4) ? L[3 * D4 + idx] : 0.f;
            if (cr == 0) {
                a0 = v0 * w; a1 = v1 * w; a2 = v2 * w; a3 = v3 * w;
            } else {
                a0 = a0 + v0 * w; a1 = a1 + v1 * w;
                a2 = a2 + v2 * w; a3 = a3 + v3 * w;
            }
        }
        x0 = a0; x1 = a1; x2 = a2; x3 = a3;
    }

    out[vbase + hw]          = x0;
    out[vbase + HW + hw]     = x1;
    out[vbase + 2 * HW + hw] = x2;
}

extern "C" void kernel_launch(void* const* d_in, const int* in_sizes, int n_in,
                              void* d_out, int out_size, void* d_ws, size_t ws_size,
                              hipStream_t stream) {
    const float* vi = (const float*)d_in[0];
    const float* ir = (const float*)d_in[1];
    const float* raw[6] = {
        (const float*)d_in[2], (const float*)d_in[3],
        (const float*)d_in[4], (const float*)d_in[5],
        (const float*)d_in[6], (const float*)d_in[7]
    };
    float* out = (float*)d_out;

    const size_t OSZ      = (size_t)RECN * 128;              // 8,912,896 B/LUT
    const size_t NEED_OCT = 6 * OSZ;                         // ~53.5 MB
    const size_t QSZ      = (size_t)QREC * 64;               // 4,734,976 B/LUT
    const size_t NEED_Q   = 6 * QSZ;                         // ~28.4 MB

    if (ws_size >= NEED_OCT) {
        char* ws = (char*)d_ws;
        int pack_blocks = (RECN * 8 + 255) / 256;            // 2176
        for (int s = 0; s < 6; ++s) {
            pack_oct<<<pack_blocks, 256, 0, stream>>>(raw[s], (s == 5) ? 3 : 4,
                                                      (float4*)(ws + s * OSZ));
        }
        fused_coop<<<NPIX / CBLK, CBLK, 0, stream>>>(vi, ir, (const float4*)ws, out);
    } else if (ws_size >= NEED_Q) {
        char* ws = (char*)d_ws;
        int pack_blocks = (QREC + 255) / 256;
        for (int s = 0; s < 6; ++s) {
            pack_quad<<<pack_blocks, 256, 0, stream>>>(raw[s], (s == 5) ? 3 : 4,
                                                       (float4*)(ws + s * QSZ));
        }
        fused_coop_q<<<NPIX / CBLK, CBLK, 0, stream>>>(vi, ir, (const float4*)ws, out);
    } else {
        fused_fallback<<<NPIX / 256, 256, 0, stream>>>(vi, ir, raw[0], raw[1], raw[2],
                                                       raw[3], raw[4], raw[5], out);
    }
}

// Round 5
// 278.778 us; speedup vs baseline: 1.9375x; 1.0458x over previous
//
#include <hip/hip_runtime.h>

// CRITICAL: bit-exact replication of the numpy fp32 oracle requires NO FMA
// contraction (hipcc default -ffp-contract=fast-honor-pragmas would fuse).
#pragma clang fp contract(off)

#define D4    83521      // 17^4 entries per LUT (per channel)
#define HW    262144     // 512*512
#define NPIX  2097152    // 8*512*512
#define QREC  73984      // 17*17*16*16 quad records per LUT (64 B each)
#define RECN  69632      // 17*16*16*16 oct records per LUT (128 B each)
#define CBLK  64         // cooperative kernel: single-wave blocks

struct SrcPtrs { const float* p[6]; };

// ---------- oct packing, ALL 6 LUTS IN ONE LAUNCH (r18) ---------------------
// r17 ran 6 serial pack_oct launches = ~104 us (36% of total): each is a
// small 557K-thread kernel, parallelism-limited and stream-serialized.
// One launch over all 6 LUTs (grid 13056 blocks exactly) restores full-GPU
// parallelism. Per-slot logic verbatim r17 pack_oct; dst[j] lands at the
// identical byte (LUT regions contiguous), so fused_coop is untouched.
// Record e = ((i0*16 + i1)*16 + i2)*16 + i3 (i1,i2,i3 in [0,16), i0 in [0,17));
// slot g (float4) holds channels of corner (i1+((g>>2)&1), i2+((g>>1)&1),
// i3+(g&1)). A pixel's 16 corners = records R(i0) and R(i0)+4096 (i0+1),
// each ONE aligned 128 B line. One float4 slot per thread -> coalesced writes.
__global__ __launch_bounds__(256) void pack_oct_all(SrcPtrs sp,
                                                    float4* __restrict__ dst) {
    const int PER = RECN * 8;                 // 557056 slots per LUT
    int j = blockIdx.x * 256 + threadIdx.x;   // [0, 6*PER), grid exact
    int s = j / PER;                          // LUT index 0..5
    int r = j - s * PER;
    int g = r & 7;                            // slot = b1*4 + b2*2 + b3
    int e = r >> 3;                           // record index
    int i3 = e & 15;
    int i2 = (e >> 4) & 15;
    int i1 = (e >> 8) & 15;
    int i0 = e >> 12;                         // [0,17)
    int o = i0 * 4913 + i1 * 289 + i2 * 17 + i3
          + ((g >> 2) & 1) * 289 + ((g >> 1) & 1) * 17 + (g & 1);
    const float* __restrict__ src = sp.p[s];
    float4 v;
    v.x = src[o];
    v.y = src[D4 + o];
    v.z = src[2 * D4 + o];
    v.w = (s != 5) ? src[3 * D4 + o] : 0.f;
    dst[j] = v;                               // fully coalesced 16 B/lane
}

// Cooperative fused 6-stage chain — BARRIER-FREE (r13 structure, OCT layout).
// VERBATIM r17 (187 us, absmax 0.0): gather at the structural floor —
// 2 x 128 B lines per pixel per stage, 8 lines per 1 KB gather instruction.
__global__ __launch_bounds__(CBLK) void fused_coop(const float* __restrict__ vi,
                                                   const float* __restrict__ ir,
                                                   const float4* __restrict__ luts,
                                                   float* __restrict__ out) {
#pragma clang fp contract(off)
    __shared__ float4 exch[CBLK * 17];  // 272 B per pixel (17-float4 rows, conflict-free)

    int tid = threadIdx.x;              // == lane (single-wave block)
    int p = blockIdx.x * CBLK + tid;
    int b  = p >> 18;                   // HW = 2^18
    int hw = p & (HW - 1);
    int vbase = (b * 3) << 18;

    float x0 = vi[vbase + hw];
    float x1 = vi[vbase + HW + hw];
    float x2 = vi[vbase + 2 * HW + hw];
    float x3 = ir[p];

    int sub  = tid >> 4;                // which pixel of each 4-px group
    int kidx = tid & 15;                // corner code: b0=(k>>2)&1, b1=(k>>3)&1,
                                        //              b2=k&1,      b3=(k>>1)&1
    int b0   = (kidx >> 2) & 1;
    int slot = ((kidx >> 3) & 1) * 4 + (kidx & 1) * 2 + ((kidx >> 1) & 1);

    for (int s = 0; s < 6; ++s) {
        // per-lane LUT base folds in i0-record select + slot (addr calc once)
        const float4* __restrict__ lutS =
            luts + (size_t)s * (RECN * 8) + b0 * (4096 * 8) + slot;

        // ---- owner: indices + weights (exact round-6 arithmetic) ----
        x0 = fminf(fmaxf(x0, 0.f), 1.f);
        x1 = fminf(fmaxf(x1, 0.f), 1.f);
        x2 = fminf(fmaxf(x2, 0.f), 1.f);
        x3 = fminf(fmaxf(x3, 0.f), 1.f);
        float xs0 = x0 * 16.f;
        float xs1 = x1 * 16.f;
        float xs2 = x2 * 16.f;
        float xs3 = x3 * 16.f;
        int i0 = (int)xs0; i0 = i0 > 15 ? 15 : i0;
        int i1 = (int)xs1; i1 = i1 > 15 ? 15 : i1;
        int i2 = (int)xs2; i2 = i2 > 15 ? 15 : i2;
        int i3 = (int)xs3; i3 = i3 > 15 ? 15 : i3;
        float f0 = xs0 - (float)i0;     // mul-then-sub, contraction OFF
        float f1 = xs1 - (float)i1;
        float f2 = xs2 - (float)i2;
        float f3 = xs3 - (float)i3;
        float g0 = 1.f - f0;
        float g1 = 1.f - f1;
        float g2 = 1.f - f2;
        float g3 = 1.f - f3;
        float w01[4] = { g0 * g1, f0 * g1, g0 * f1, f0 * f1 };

        int r00 = ((i0 * 16 + i1) * 16 + i2) * 16 + i3;   // oct record index

        // ---- r00 exchange: pure in-wave shuffle, no LDS / no barrier ----
        int r0s[16];
#pragma unroll
        for (int t = 0; t < 16; ++t)
            r0s[t] = __shfl(r00, 4 * t + sub, 64);

        // ---- cooperative gather: 16 loads/lane, 8 x 128 B lines/instr ----
        float4 v[16];
#pragma unroll
        for (int t = 0; t < 16; ++t)
            v[t] = lutS[(size_t)r0s[t] * 8];
        __builtin_amdgcn_sched_barrier(0);   // keep the 16-deep load batch intact

        // ---- in-wave fragment exchange (DS ops in order per wave) ----
#pragma unroll
        for (int t = 0; t < 16; ++t)
            exch[(4 * t + sub) * 17 + kidx] = v[t];
        __builtin_amdgcn_sched_barrier(0);   // pin write->read program order

        // ---- owner: exact round-6 sequential accumulation ----
        const float4* myb = &exch[tid * 17];
        float a0 = 0.f, a1 = 0.f, a2 = 0.f, a3 = 0.f;
#pragma unroll
        for (int hi = 0; hi < 2; ++hi) {     // b3
            float w3 = hi ? f3 : g3;
#pragma unroll
            for (int c = 0; c < 8; ++c) {    // b0=c&1, b1=(c>>1)&1, b2=c>>2
                int k = ((c & 3) << 2) + ((c >> 2) + 2 * hi);  // 4b0+8b1+b2+2b3
                float4 vv = myb[k];
                float w012 = w01[c & 3] * ((c >> 2) ? f2 : g2);
                float w    = w012 * w3;
                if (hi == 0 && c == 0) {
                    a0 = vv.x * w; a1 = vv.y * w; a2 = vv.z * w; a3 = vv.w * w;
                } else {
                    a0 = a0 + vv.x * w; a1 = a1 + vv.y * w;
                    a2 = a2 + vv.z * w; a3 = a3 + vv.w * w;
                }
            }
        }
        __builtin_amdgcn_sched_barrier(0);   // reads done before next stage's writes
        x0 = a0; x1 = a1; x2 = a2; x3 = a3;
    }

    out[vbase + hw]          = x0;
    out[vbase + HW + hw]     = x1;
    out[vbase + 2 * HW + hw] = x2;
}

// ---------- quad tier (proven r13, 285 us coop): fallback if ws < 53.5 MB ---
__global__ __launch_bounds__(256) void pack_quad(const float* __restrict__ src,
                                                 int n_ch,
                                                 float4* __restrict__ dst) {
    int e = blockIdx.x * 256 + threadIdx.x;
    if (e >= QREC) return;
    int i3 = e & 15;
    int i2 = (e >> 4) & 15;
    int t  = e >> 8;              // i0*17 + i1
    int i0 = t / 17;
    int i1 = t - i0 * 17;
    int base = i0 * 4913 + i1 * 289 + i2 * 17 + i3;
    float4* rec = dst + (size_t)e * 4;
#pragma unroll
    for (int g = 0; g < 4; ++g) {
        int o = base + (g & 1) * 17 + (g >> 1);
        float4 v;
        v.x = src[o];
        v.y = src[D4 + o];
        v.z = src[2 * D4 + o];
        v.w = (n_ch == 4) ? src[3 * D4 + o] : 0.f;
        rec[g] = v;
    }
}

__global__ __launch_bounds__(CBLK) void fused_coop_q(const float* __restrict__ vi,
                                                     const float* __restrict__ ir,
                                                     const float4* __restrict__ luts,
                                                     float* __restrict__ out) {
#pragma clang fp contract(off)
    __shared__ float4 exch[CBLK * 17];

    int tid = threadIdx.x;
    int p = blockIdx.x * CBLK + tid;
    int b  = p >> 18;
    int hw = p & (HW - 1);
    int vbase = (b * 3) << 18;

    float x0 = vi[vbase + hw];
    float x1 = vi[vbase + HW + hw];
    float x2 = vi[vbase + 2 * HW + hw];
    float x3 = ir[p];

    int rec     = (tid >> 2) & 3;
    int slot    = tid & 3;
    int rec_off = ((rec & 1) ? 4352 : 0) + ((rec & 2) ? 256 : 0);
    int sub     = tid >> 4;
    int kidx    = tid & 15;

    for (int s = 0; s < 6; ++s) {
        const float4* __restrict__ lutS =
            luts + (size_t)s * QREC * 4 + (size_t)rec_off * 4 + slot;

        x0 = fminf(fmaxf(x0, 0.f), 1.f);
        x1 = fminf(fmaxf(x1, 0.f), 1.f);
        x2 = fminf(fmaxf(x2, 0.f), 1.f);
        x3 = fminf(fmaxf(x3, 0.f), 1.f);
        float xs0 = x0 * 16.f;
        float xs1 = x1 * 16.f;
        float xs2 = x2 * 16.f;
        float xs3 = x3 * 16.f;
        int i0 = (int)xs0; i0 = i0 > 15 ? 15 : i0;
        int i1 = (int)xs1; i1 = i1 > 15 ? 15 : i1;
        int i2 = (int)xs2; i2 = i2 > 15 ? 15 : i2;
        int i3 = (int)xs3; i3 = i3 > 15 ? 15 : i3;
        float f0 = xs0 - (float)i0;
        float f1 = xs1 - (float)i1;
        float f2 = xs2 - (float)i2;
        float f3 = xs3 - (float)i3;
        float g0 = 1.f - f0;
        float g1 = 1.f - f1;
        float g2 = 1.f - f2;
        float g3 = 1.f - f3;
        float w01[4] = { g0 * g1, f0 * g1, g0 * f1, f0 * f1 };

        int r00 = ((i0 * 17 + i1) * 16 + i2) * 16 + i3;

        int r0s[16];
#pragma unroll
        for (int t = 0; t < 16; ++t)
            r0s[t] = __shfl(r00, 4 * t + sub, 64);

        float4 v[16];
#pragma unroll
        for (int t = 0; t < 16; ++t)
            v[t] = lutS[(size_t)r0s[t] * 4];
        __builtin_amdgcn_sched_barrier(0);

#pragma unroll
        for (int t = 0; t < 16; ++t)
            exch[(4 * t + sub) * 17 + kidx] = v[t];
        __builtin_amdgcn_sched_barrier(0);

        const float4* myb = &exch[tid * 17];
        float a0 = 0.f, a1 = 0.f, a2 = 0.f, a3 = 0.f;
#pragma unroll
        for (int hi = 0; hi < 2; ++hi) {
            float w3 = hi ? f3 : g3;
#pragma unroll
            for (int c = 0; c < 8; ++c) {
                int k = ((c & 3) << 2) + ((c >> 2) + 2 * hi);
                float4 vv = myb[k];
                float w012 = w01[c & 3] * ((c >> 2) ? f2 : g2);
                float w    = w012 * w3;
                if (hi == 0 && c == 0) {
                    a0 = vv.x * w; a1 = vv.y * w; a2 = vv.z * w; a3 = vv.w * w;
                } else {
                    a0 = a0 + vv.x * w; a1 = a1 + vv.y * w;
                    a2 = a2 + vv.z * w; a3 = a3 + vv.w * w;
                }
            }
        }
        __builtin_amdgcn_sched_barrier(0);
        x0 = a0; x1 = a1; x2 = a2; x3 = a3;
    }

    out[vbase + hw]          = x0;
    out[vbase + HW + hw]     = x1;
    out[vbase + 2 * HW + hw] = x2;
}

// ---------- raw fallback (no workspace) -------------------------------------
__global__ __launch_bounds__(256) void fused_fallback(const float* __restrict__ vi,
                                                      const float* __restrict__ ir,
                                                      const float* __restrict__ l8,
                                                      const float* __restrict__ l00,
                                                      const float* __restrict__ l01,
                                                      const float* __restrict__ l02,
                                                      const float* __restrict__ l03,
                                                      const float* __restrict__ lpgf,
                                                      float* __restrict__ out) {
#pragma clang fp contract(off)
    int p = blockIdx.x * 256 + threadIdx.x;
    if (p >= NPIX) return;
    int b  = p >> 18;
    int hw = p & (HW - 1);
    int vbase = (b * 3) << 18;

    const float* ptrs[6] = { l8, l00, l01, l02, l03, lpgf };

    float x0 = vi[vbase + hw];
    float x1 = vi[vbase + HW + hw];
    float x2 = vi[vbase + 2 * HW + hw];
    float x3 = ir[p];

    for (int s = 0; s < 6; ++s) {
        const float* __restrict__ L = ptrs[s];
        int n_ch = (s == 5) ? 3 : 4;
        x0 = fminf(fmaxf(x0, 0.f), 1.f);
        x1 = fminf(fmaxf(x1, 0.f), 1.f);
        x2 = fminf(fmaxf(x2, 0.f), 1.f);
        x3 = fminf(fmaxf(x3, 0.f), 1.f);
        float xs0 = x0 * 16.f;
        float xs1 = x1 * 16.f;
        float xs2 = x2 * 16.f;
        float xs3 = x3 * 16.f;
        int i0 = (int)xs0; i0 = i0 > 15 ? 15 : i0;
        int i1 = (int)xs1; i1 = i1 > 15 ? 15 : i1;
        int i2 = (int)xs2; i2 = i2 > 15 ? 15 : i2;
        int i3 = (int)xs3; i3 = i3 > 15 ? 15 : i3;
        float f0 = xs0 - (float)i0;
        float f1 = xs1 - (float)i1;
        float f2 = xs2 - (float)i2;
        float f3 = xs3 - (float)i3;
        float g0 = 1.f - f0;
        float g1 = 1.f - f1;
        float g2 = 1.f - f2;
        float g3 = 1.f - f3;
        float w01[4] = { g0 * g1, f0 * g1, g0 * f1, f0 * f1 };
        int off = i0 * 4913 + i1 * 289 + i2 * 17 + i3;
        float a0 = 0.f, a1 = 0.f, a2 = 0.f, a3 = 0.f;
        for (int cr = 0; cr < 16; ++cr) {
            int hi = cr >> 3, c = cr & 7;
            int idx = off + (c & 1) * 4913 + ((c >> 1) & 1) * 289 + (c >> 2) * 17 + hi;
            float w012 = w01[c & 3] * ((c >> 2) ? f2 : g2);
            float w    = w012 * (hi ? f3 : g3);
            float v0 = L[idx];
            float v1 = L[D4 + idx];
            float v2 = L[2 * D4 + idx];
            float v3 = (n_ch == 4) ? L[3 * D4 + idx] : 0.f;
            if (cr == 0) {
                a0 = v0 * w; a1 = v1 * w; a2 = v2 * w; a3 = v3 * w;
            } else {
                a0 = a0 + v0 * w; a1 = a1 + v1 * w;
                a2 = a2 + v2 * w; a3 = a3 + v3 * w;
            }
        }
        x0 = a0; x1 = a1; x2 = a2; x3 = a3;
    }

    out[vbase + hw]          = x0;
    out[vbase + HW + hw]     = x1;
    out[vbase + 2 * HW + hw] = x2;
}

extern "C" void kernel_launch(void* const* d_in, const int* in_sizes, int n_in,
                              void* d_out, int out_size, void* d_ws, size_t ws_size,
                              hipStream_t stream) {
    const float* vi = (const float*)d_in[0];
    const float* ir = (const float*)d_in[1];
    const float* raw[6] = {
        (const float*)d_in[2], (const float*)d_in[3],
        (const float*)d_in[4], (const float*)d_in[5],
        (const float*)d_in[6], (const float*)d_in[7]
    };
    float* out = (float*)d_out;

    const size_t OSZ      = (size_t)RECN * 128;              // 8,912,896 B/LUT
    const size_t NEED_OCT = 6 * OSZ;                         // ~53.5 MB
    const size_t QSZ      = (size_t)QREC * 64;               // 4,734,976 B/LUT
    const size_t NEED_Q   = 6 * QSZ;                         // ~28.4 MB

    if (ws_size >= NEED_OCT) {
        SrcPtrs sp;
        for (int s = 0; s < 6; ++s) sp.p[s] = raw[s];
        int pack_blocks = 6 * RECN * 8 / 256;                // 13056, exact
        pack_oct_all<<<pack_blocks, 256, 0, stream>>>(sp, (float4*)d_ws);
        fused_coop<<<NPIX / CBLK, CBLK, 0, stream>>>(vi, ir, (const float4*)d_ws, out);
    } else if (ws_size >= NEED_Q) {
        char* ws = (char*)d_ws;
        int pack_blocks = (QREC + 255) / 256;
        for (int s = 0; s < 6; ++s) {
            pack_quad<<<pack_blocks, 256, 0, stream>>>(raw[s], (s == 5) ? 3 : 4,
                                                       (float4*)(ws + s * QSZ));
        }
        fused_coop_q<<<NPIX / CBLK, CBLK, 0, stream>>>(vi, ir, (const float4*)ws, out);
    } else {
        fused_fallback<<<NPIX / 256, 256, 0, stream>>>(vi, ir, raw[0], raw[1], raw[2],
                                                       raw[3], raw[4], raw[5], out);
    }
}